// Round 6
// baseline (168.274 us; speedup 1.0000x reference)
//
#include <hip/hip_runtime.h>

typedef __bf16 bf16x8 __attribute__((ext_vector_type(8)));
typedef float f32x4 __attribute__((ext_vector_type(4)));
typedef unsigned int u32;

#define IN_STRIDE 152  // lds input row stride (elems); 304B = 16B-aligned rows
#define IN_ROWS   31   // 16 out rows + 14 halo + 1 row for kh=15 zero-pad slot
#define IN_SLOTS  36   // float4 col slots per row: cols [c0q-8, c0q+136) = 144

__device__ __forceinline__ unsigned short f2bf(float f) {
    u32 u = __builtin_bit_cast(u32, f);
    return (unsigned short)((u + 0x7FFFu + ((u >> 16) & 1u)) >> 16);  // RNE
}
__device__ __forceinline__ int refl(int i) {  // reflect index into [0,512)
    return i < 0 ? -i : (i > 511 ? 1022 - i : i);
}

// Block (x=half, y=h0/16, z=n): sample n, rows h0..h0+15, cols [256*half, 256*half+256)
// as 2 chunks of 128. Wave w owns cols [16w,16w+16) of each 64-col subtile.
// K = 15x15 taps padded to 16x16 = 256 = 8 MFMA K-steps (r2 mapping, HW-validated):
// k = 32*ks + 8*g + j  ->  kh = 2*ks + (g>>1), kw = 8*(g&1) + j   (g = lane>>4)
// MODE 0: conv -> per-block max -> partial[b].
// MODE 1: reduce partials -> scale; conv -> scaled direct float4 stores.
template <int MODE>
__global__ __launch_bounds__(256, 4) void dynconv(const float* __restrict__ x,
                                                  const float* __restrict__ kern,
                                                  float* __restrict__ out,
                                                  float* __restrict__ partial) {
    __shared__ __align__(16) unsigned short lds_in[IN_ROWS * IN_STRIDE];  // 9424B
    __shared__ float wm[4];

    const int tid  = threadIdx.x;
    const int lane = tid & 63;
    const int wave = tid >> 6;
    const int half = blockIdx.x;            // 0/1: which 256-col half
    const int h0   = blockIdx.y * 16;
    const int n    = blockIdx.z;
    const int hbase = half * 256;

    const float* xs = x + (size_t)n * (16u * 512u * 512u);

    // ---- A fragments: kernel weights, zero-padded to 16x16 taps ----
    const int oca = lane & 15;
    const int g   = lane >> 4;
    const int g1  = g & 1;
    const int g2  = g >> 1;
    bf16x8 afrag[8];
    {
        const float* kp = kern + ((size_t)n * 16 + oca) * 225;
        #pragma unroll
        for (int ks = 0; ks < 8; ++ks) {
            const int kh = 2 * ks + g2;
            #pragma unroll
            for (int j = 0; j < 8; ++j) {
                const int kwv = 8 * g1 + j;
                float v = 0.f;
                if (kh < 15 && kwv < 15) v = kp[kh * 15 + kwv];
                afrag[ks][j] = (__bf16)v;
            }
        }
    }

    // ---- MODE 1: per-sample max from the 64 partials of sample n ----
    float scale = 0.f;
    if constexpr (MODE == 1) {
        float pv = partial[(n << 6) + lane];
        #pragma unroll
        for (int off = 32; off > 0; off >>= 1) pv = fmaxf(pv, __shfl_xor(pv, off, 64));
        scale = 1.0f / pv;
    }

    const int hh = lane & 15;               // B n-dim: output row offset
    const int colbase0 = wave * 16 + g1 * 8;

    // ---- stage a 31 x 144 tile (cols c0q-8 .. c0q+135), reflect, f32->bf16 ----
    auto stage = [&](int c0q) {
        for (int idx = tid; idx < IN_ROWS * IN_SLOTS; idx += 256) {
            const int rr = idx / IN_SLOTS;
            const int cs = idx - rr * IN_SLOTS;
            const float* rowp = xs + refl(h0 - 7 + rr) * 512;
            const int gc0 = c0q - 8 + 4 * cs;
            float v0, v1, v2, v3;
            if (gc0 >= 0 && gc0 <= 508) {           // aligned interior fast path
                const float4 v = *(const float4*)(rowp + gc0);
                v0 = v.x; v1 = v.y; v2 = v.z; v3 = v.w;
            } else {                                // border reflect, scalar
                v0 = rowp[refl(gc0)];
                v1 = rowp[refl(gc0 + 1)];
                v2 = rowp[refl(gc0 + 2)];
                v3 = rowp[refl(gc0 + 3)];
            }
            const u32 lo = (u32)f2bf(v0) | ((u32)f2bf(v1) << 16);
            const u32 hi = (u32)f2bf(v2) | ((u32)f2bf(v3) << 16);
            *(uint2*)&lds_in[rr * IN_STRIDE + 4 * cs] = make_uint2(lo, hi);
        }
    };

    // ---- conv of one 16h x 64w subtile at col offset w0*64 within staged tile ----
    auto conv = [&](int w0, f32x4* acc) {
        #pragma unroll
        for (int t = 0; t < 16; ++t) acc[t] = f32x4{0.f, 0.f, 0.f, 0.f};
        const int colbase = w0 * 64 + colbase0;
        #pragma unroll
        for (int ks = 0; ks < 8; ++ks) {
            const int row = hh + 2 * ks + g2;
            const unsigned short* rp = &lds_in[row * IN_STRIDE + colbase];
            const uint4 R0 = *(const uint4*)(rp);
            const uint4 R1 = *(const uint4*)(rp + 8);
            const uint4 R2 = *(const uint4*)(rp + 16);
            const u32 E[12] = {R0.x, R0.y, R0.z, R0.w, R1.x, R1.y, R1.z, R1.w,
                               R2.x, R2.y, R2.z, R2.w};
            #pragma unroll
            for (int t = 0; t < 16; ++t) {   // window shift s = t+1 (stage at -8)
                const int s  = t + 1;
                const int xb = s >> 1;
                u32 d0, d1, d2, d3;
                if (s & 1) {
                    d0 = __builtin_amdgcn_alignbit(E[xb + 1], E[xb], 16);
                    d1 = __builtin_amdgcn_alignbit(E[xb + 2], E[xb + 1], 16);
                    d2 = __builtin_amdgcn_alignbit(E[xb + 3], E[xb + 2], 16);
                    d3 = __builtin_amdgcn_alignbit(E[xb + 4], E[xb + 3], 16);
                } else {
                    d0 = E[xb]; d1 = E[xb + 1]; d2 = E[xb + 2]; d3 = E[xb + 3];
                }
                uint4 dv; dv.x = d0; dv.y = d1; dv.z = d2; dv.w = d3;
                acc[t] = __builtin_amdgcn_mfma_f32_16x16x32_bf16(
                    afrag[ks], __builtin_bit_cast(bf16x8, dv), acc[t], 0, 0, 0);
            }
        }
    };

    float m = -3.4e38f;
    #pragma unroll 1
    for (int ch = 0; ch < 2; ++ch) {
        __syncthreads();
        stage(hbase + ch * 128);
        __syncthreads();
        #pragma unroll 1
        for (int w0 = 0; w0 < 2; ++w0) {
            f32x4 acc[16];
            conv(w0, acc);
            if constexpr (MODE == 0) {
                #pragma unroll
                for (int t = 0; t < 16; ++t)
                    #pragma unroll
                    for (int r = 0; r < 4; ++r) m = fmaxf(m, acc[t][r]);
            } else {
                // direct stores: lane owns w = wave*16 + t, t=0..15 (64B/line per lane)
                #pragma unroll
                for (int r = 0; r < 4; ++r) {
                    const int oc = 4 * g + r;
                    float* rowp = out + (((size_t)(oc * 16 + n)) * 512 + (h0 + hh)) * 512
                                  + hbase + ch * 128 + w0 * 64 + wave * 16;
                    #pragma unroll
                    for (int q = 0; q < 4; ++q) {
                        f32x4 v;
                        v[0] = acc[4 * q + 0][r] * scale;
                        v[1] = acc[4 * q + 1][r] * scale;
                        v[2] = acc[4 * q + 2][r] * scale;
                        v[3] = acc[4 * q + 3][r] * scale;
                        *(f32x4*)(rowp + 4 * q) = v;
                    }
                }
            }
        }
    }

    if constexpr (MODE == 0) {
        #pragma unroll
        for (int off = 32; off > 0; off >>= 1) m = fmaxf(m, __shfl_xor(m, off, 64));
        if (lane == 0) wm[wave] = m;
        __syncthreads();
        if (tid == 0)
            partial[((blockIdx.z * 32 + blockIdx.y) << 1) + blockIdx.x] =
                fmaxf(fmaxf(wm[0], wm[1]), fmaxf(wm[2], wm[3]));
    }
}

extern "C" void kernel_launch(void* const* d_in, const int* in_sizes, int n_in,
                              void* d_out, int out_size, void* d_ws, size_t ws_size,
                              hipStream_t stream) {
    (void)in_sizes; (void)n_in; (void)out_size; (void)ws_size;
    const float* x  = (const float*)d_in[0];
    const float* k  = (const float*)d_in[1];
    float* out      = (float*)d_out;
    float* partial  = (float*)d_ws;          // 1024 floats

    dim3 grid(2, 32, 16);   // (col half, h-tile, sample) = 1024 blocks = 4/CU
    dim3 block(256);
    dynconv<0><<<grid, block, 0, stream>>>(x, k, out, partial);  // max pass
    dynconv<1><<<grid, block, 0, stream>>>(x, k, out, partial);  // scale+store pass
}